// Round 1
// 2984.509 us; speedup vs baseline: 1.9112x; 1.9112x over previous
//
#include <hip/hip_runtime.h>

#define DD   128   // feature dim
#define TRE  128   // edges per block (edge kernel)
#define PX   130   // transposed xs/ht pitch (bank: (2k+row)%32 -> 2-way = free)
#define PO   132   // epilogue ob pitch (row-major, 16B-aligned rows for float4)
#define TR   64    // node kernel rows per block (unchanged)
#define LDH  65    // node kernel transposed h stride

// Edge-kernel LDS layout (dwords):
#define XS_DW   16896          // max(128*130, 128*132) region: xs/ht alias ob
#define RED1_DW (XS_DW)        // [4][128]
#define RED2_DW (XS_DW + 512)  // [4][128]
#define SNDL_DW (XS_DW + 1024) // [128] int
#define RCVL_DW (XS_DW + 1152) // [128] int
#define SM_DW   (XS_DW + 1280) // 18176 dwords = 72704 B -> 2 blocks/CU

// ---------------------------------------------------------------------------
// Edge MLP, v2: 128 edges/block, 4 waves, each wave owns a 32-col chunk and
// TWO row-groups (rows lane and 64+lane) -> each weight load feeds 128 FMAs
// (2x the old 64). Inputs staged into LDS transposed with coalesced float4
// loads (2 rows x 512B contiguous per wave instruction) instead of per-lane
// 64-line gathers. Epilogue routes new_e through LDS to an edge-major layout
// so out_e stores and agg atomics are line-coalesced (16 lines/instr vs 64).
// ---------------------------------------------------------------------------
__global__ __launch_bounds__(256, 2) void edge_mlp_kernel(
    const float* __restrict__ node, const float* __restrict__ efeat,
    const int* __restrict__ snd, const int* __restrict__ rcv,
    const float* __restrict__ w1, const float* __restrict__ b1,
    const float* __restrict__ w2, const float* __restrict__ b2,
    const float* __restrict__ w3, const float* __restrict__ b3,
    const float* __restrict__ gg, const float* __restrict__ bb,
    float* __restrict__ out_e, float* __restrict__ agg, int E)
{
    extern __shared__ float sm[];
    float* xs   = sm;                    // transposed x / ht, aliased as ob
    float* red1 = sm + RED1_DW;
    float* red2 = sm + RED2_DW;
    int*   sndl = (int*)(sm + SNDL_DW);
    int*   rcvl = (int*)(sm + RCVL_DW);

    const int tid  = (int)threadIdx.x;
    const int lane = tid & 63;
    const int c0   = __builtin_amdgcn_readfirstlane((tid >> 6) << 5);
    const long e0  = (long)blockIdx.x * TRE;

    if (tid < TRE) {
        long e = e0 + tid; if (e >= E) e = E - 1;
        sndl[tid] = snd[e];
        rcvl[tid] = rcv[e];
    }
    __syncthreads();

    const int srow = tid >> 5;          // 0..7 (2 rows per wave per pass)
    const int k4   = (tid & 31) << 2;   // 0,4,...,124

    float accA[32], accB[32];

    // Stage one 128x128 input block transposed into xs.
    // Wave instruction = 2 random rows x 512B contiguous -> coalesced.
    auto stage = [&](const float* __restrict__ base, const int* __restrict__ idx) {
#pragma unroll
        for (int it = 0; it < 16; ++it) {
            const int r = (it << 3) + srow;
            long rowid;
            if (idx) rowid = idx[r];
            else { long e = e0 + r; if (e >= E) e = E - 1; rowid = e; }
            const float4 v = *(const float4*)(base + rowid * DD + k4);
            xs[(k4 + 0) * PX + r] = v.x;
            xs[(k4 + 1) * PX + r] = v.y;
            xs[(k4 + 2) * PX + r] = v.z;
            xs[(k4 + 3) * PX + r] = v.w;
        }
    };

    // 128-K GEMM block: weights wave-uniform (scalar path), x from LDS.
    auto gemm128 = [&](const float* __restrict__ W) {
#pragma unroll 2
        for (int k = 0; k < DD; ++k) {
            const float xa = xs[k * PX + lane];
            const float xb = xs[k * PX + 64 + lane];
            const float* wr = W + k * DD;
#pragma unroll
            for (int i = 0; i < 32; ++i) {
                accA[i] = fmaf(wr[i], xa, accA[i]);
                accB[i] = fmaf(wr[i], xb, accB[i]);
            }
        }
    };

    // ---- layer 1: [v_i | v_j | ef] @ ew1 + eb1, relu ----
#pragma unroll
    for (int i = 0; i < 32; ++i) { const float b = b1[c0 + i]; accA[i] = b; accB[i] = b; }
    stage(node, sndl);              __syncthreads();
    gemm128(w1 + c0);               __syncthreads();
    stage(node, rcvl);              __syncthreads();
    gemm128(w1 + 128 * DD + c0);    __syncthreads();
    stage(efeat, nullptr);          __syncthreads();
    gemm128(w1 + 256 * DD + c0);    __syncthreads();
#pragma unroll
    for (int i = 0; i < 32; ++i) {
        xs[(c0 + i) * PX + lane]      = fmaxf(accA[i], 0.f);
        xs[(c0 + i) * PX + 64 + lane] = fmaxf(accB[i], 0.f);
    }
    __syncthreads();

    // ---- layer 2 ----
#pragma unroll
    for (int i = 0; i < 32; ++i) { const float b = b2[c0 + i]; accA[i] = b; accB[i] = b; }
    gemm128(w2 + c0);
    __syncthreads();                 // all ht reads done before overwrite
#pragma unroll
    for (int i = 0; i < 32; ++i) {
        xs[(c0 + i) * PX + lane]      = fmaxf(accA[i], 0.f);
        xs[(c0 + i) * PX + 64 + lane] = fmaxf(accB[i], 0.f);
    }
    __syncthreads();

    // ---- layer 3 (no relu) ----
#pragma unroll
    for (int i = 0; i < 32; ++i) { const float b = b3[c0 + i]; accA[i] = b; accB[i] = b; }
    gemm128(w3 + c0);

    // ---- LayerNorm: 4 wave-partials per row via LDS ----
    float s1a = 0.f, s2a = 0.f, s1b = 0.f, s2b = 0.f;
#pragma unroll
    for (int i = 0; i < 32; ++i) {
        s1a += accA[i]; s2a += accA[i] * accA[i];
        s1b += accB[i]; s2b += accB[i] * accB[i];
    }
    const int w = tid >> 6;
    red1[w * 128 + lane] = s1a;  red1[w * 128 + 64 + lane] = s1b;
    red2[w * 128 + lane] = s2a;  red2[w * 128 + 64 + lane] = s2b;
    __syncthreads();                 // also fences last ht reads vs ob writes
    const float S1a = red1[lane] + red1[128 + lane] + red1[256 + lane] + red1[384 + lane];
    const float S2a = red2[lane] + red2[128 + lane] + red2[256 + lane] + red2[384 + lane];
    const float S1b = red1[64 + lane] + red1[192 + lane] + red1[320 + lane] + red1[448 + lane];
    const float S2b = red2[64 + lane] + red2[192 + lane] + red2[320 + lane] + red2[448 + lane];
    const float muA = S1a * (1.0f / 128.0f);
    const float rsA = rsqrtf(S2a * (1.0f / 128.0f) - muA * muA + 1e-5f);
    const float muB = S1b * (1.0f / 128.0f);
    const float rsB = rsqrtf(S2b * (1.0f / 128.0f) - muB * muB + 1e-5f);

    // ---- LN apply -> edge-major ob (aliases xs; ht dead) ----
#pragma unroll
    for (int i = 0; i < 32; i += 4) {
        float4 oa, oc;
        oa.x = (accA[i + 0] - muA) * rsA * gg[c0 + i + 0] + bb[c0 + i + 0];
        oa.y = (accA[i + 1] - muA) * rsA * gg[c0 + i + 1] + bb[c0 + i + 1];
        oa.z = (accA[i + 2] - muA) * rsA * gg[c0 + i + 2] + bb[c0 + i + 2];
        oa.w = (accA[i + 3] - muA) * rsA * gg[c0 + i + 3] + bb[c0 + i + 3];
        oc.x = (accB[i + 0] - muB) * rsB * gg[c0 + i + 0] + bb[c0 + i + 0];
        oc.y = (accB[i + 1] - muB) * rsB * gg[c0 + i + 1] + bb[c0 + i + 1];
        oc.z = (accB[i + 2] - muB) * rsB * gg[c0 + i + 2] + bb[c0 + i + 2];
        oc.w = (accB[i + 3] - muB) * rsB * gg[c0 + i + 3] + bb[c0 + i + 3];
        *(float4*)&xs[lane * PO + c0 + i]        = oa;
        *(float4*)&xs[(64 + lane) * PO + c0 + i] = oc;
    }
    __syncthreads();

    // ---- coalesced epilogue: out_e store + line-coalesced agg atomics ----
    const int lane5 = tid & 31;
#pragma unroll 2
    for (int it = 0; it < 16; ++it) {
        const int r = (it << 3) + srow;
        const long e = e0 + r;
        if (e < E) {
            const float4 v  = *(const float4*)&xs[r * PO + (lane5 << 2)];
            const long  off = e * DD + (lane5 << 2);
            const float4 fe = *(const float4*)(efeat + off);
            float4 o;
            o.x = v.x + fe.x; o.y = v.y + fe.y; o.z = v.z + fe.z; o.w = v.w + fe.w;
            *(float4*)(out_e + off) = o;
            float* ap = agg + (long)rcvl[r] * DD + (lane5 << 2);
            atomicAdd(ap + 0, v.x);   // segment-sum of new_e (pre-residual)
            atomicAdd(ap + 1, v.y);
            atomicAdd(ap + 2, v.z);
            atomicAdd(ap + 3, v.w);
        }
    }
}

// ---------------------------------------------------------------------------
// Node MLP: unchanged from the previous (verified) version.
// ---------------------------------------------------------------------------
__global__ __launch_bounds__(256, 4) void node_mlp_kernel(
    const float* __restrict__ node, const float* __restrict__ agg,
    const float* __restrict__ w1, const float* __restrict__ b1,
    const float* __restrict__ w2, const float* __restrict__ b2,
    const float* __restrict__ w3, const float* __restrict__ b3,
    const float* __restrict__ gg, const float* __restrict__ bb,
    float* __restrict__ out_n, int N)
{
    __shared__ float ht[DD * LDH];
    __shared__ float red1[4 * TR];
    __shared__ float red2[4 * TR];

    const int tid = (int)threadIdx.x;
    const int row = tid & 63;
    const int c0  = __builtin_amdgcn_readfirstlane((tid >> 6) << 5);
    const long n0 = (long)blockIdx.x * TR;
    const int  n  = (int)n0 + row;
    const bool valid = (n < N);
    const int  nS = valid ? n : 0;

    const float* vn = node + (long)nS * DD;
    const float* va = agg  + (long)nS * DD;

    float acc[32];

#pragma unroll
    for (int i = 0; i < 32; ++i) acc[i] = b1[c0 + i];
    {
        const float* W = w1 + c0;
#pragma unroll 4
        for (int k = 0; k < DD; ++k) {
            const float xk = vn[k];
            const float* wr = W + k * DD;
#pragma unroll
            for (int i = 0; i < 32; ++i) acc[i] = fmaf(wr[i], xk, acc[i]);
        }
    }
    {
        const float* W = w1 + 128 * DD + c0;
#pragma unroll 4
        for (int k = 0; k < DD; ++k) {
            const float xk = va[k];
            const float* wr = W + k * DD;
#pragma unroll
            for (int i = 0; i < 32; ++i) acc[i] = fmaf(wr[i], xk, acc[i]);
        }
    }
#pragma unroll
    for (int i = 0; i < 32; ++i) ht[(c0 + i) * LDH + row] = fmaxf(acc[i], 0.f);
    __syncthreads();

#pragma unroll
    for (int i = 0; i < 32; ++i) acc[i] = b2[c0 + i];
    {
        const float* W = w2 + c0;
#pragma unroll 4
        for (int k = 0; k < DD; ++k) {
            const float xk = ht[k * LDH + row];
            const float* wr = W + k * DD;
#pragma unroll
            for (int i = 0; i < 32; ++i) acc[i] = fmaf(wr[i], xk, acc[i]);
        }
    }
    __syncthreads();
#pragma unroll
    for (int i = 0; i < 32; ++i) ht[(c0 + i) * LDH + row] = fmaxf(acc[i], 0.f);
    __syncthreads();

#pragma unroll
    for (int i = 0; i < 32; ++i) acc[i] = b3[c0 + i];
    {
        const float* W = w3 + c0;
#pragma unroll 4
        for (int k = 0; k < DD; ++k) {
            const float xk = ht[k * LDH + row];
            const float* wr = W + k * DD;
#pragma unroll
            for (int i = 0; i < 32; ++i) acc[i] = fmaf(wr[i], xk, acc[i]);
        }
    }

    float s1 = 0.f, s2 = 0.f;
#pragma unroll
    for (int i = 0; i < 32; ++i) { s1 += acc[i]; s2 += acc[i] * acc[i]; }
    red1[(tid >> 6) * TR + row] = s1;
    red2[(tid >> 6) * TR + row] = s2;
    __syncthreads();
    const float S1 = red1[row] + red1[TR + row] + red1[2 * TR + row] + red1[3 * TR + row];
    const float S2 = red2[row] + red2[TR + row] + red2[2 * TR + row] + red2[3 * TR + row];
    const float mu   = S1 * (1.0f / 128.0f);
    const float var  = S2 * (1.0f / 128.0f) - mu * mu;
    const float rstd = rsqrtf(var + 1e-5f);

    if (valid) {
        float*       op = out_n + (long)n * DD + c0;
        const float* nr = node  + (long)n * DD + c0;
#pragma unroll
        for (int i = 0; i < 32; i += 4) {
            float4 o;
            o.x = (acc[i + 0] - mu) * rstd * gg[c0 + i + 0] + bb[c0 + i + 0] + nr[i + 0];
            o.y = (acc[i + 1] - mu) * rstd * gg[c0 + i + 1] + bb[c0 + i + 1] + nr[i + 1];
            o.z = (acc[i + 2] - mu) * rstd * gg[c0 + i + 2] + bb[c0 + i + 2] + nr[i + 2];
            o.w = (acc[i + 3] - mu) * rstd * gg[c0 + i + 3] + bb[c0 + i + 3] + nr[i + 3];
            *(float4*)(op + i) = o;
        }
    }
}

extern "C" void kernel_launch(void* const* d_in, const int* in_sizes, int n_in,
                              void* d_out, int out_size, void* d_ws, size_t ws_size,
                              hipStream_t stream)
{
    const float* node  = (const float*)d_in[0];
    const float* efeat = (const float*)d_in[1];
    const int*   snd   = (const int*)d_in[2];
    const int*   rcv   = (const int*)d_in[3];
    const float* ew1 = (const float*)d_in[4],  *eb1 = (const float*)d_in[5];
    const float* ew2 = (const float*)d_in[6],  *eb2 = (const float*)d_in[7];
    const float* ew3 = (const float*)d_in[8],  *eb3 = (const float*)d_in[9];
    const float* eg  = (const float*)d_in[10], *ebeta = (const float*)d_in[11];
    const float* nw1 = (const float*)d_in[12], *nb1 = (const float*)d_in[13];
    const float* nw2 = (const float*)d_in[14], *nb2 = (const float*)d_in[15];
    const float* nw3 = (const float*)d_in[16], *nb3 = (const float*)d_in[17];
    const float* ng  = (const float*)d_in[18], *nbeta = (const float*)d_in[19];

    const int N = in_sizes[0] / DD;   // 100000
    const int E = in_sizes[2];        // 600000

    float* agg   = (float*)d_ws;                  // N*DD floats of scratch
    float* out_n = (float*)d_out;                 // new_n + node  (N*DD)
    float* out_e = (float*)d_out + (long)N * DD;  // new_e + ef    (E*DD)

    // ws is re-poisoned before every launch -> zero the accumulator
    hipMemsetAsync(agg, 0, (size_t)N * DD * sizeof(float), stream);

    const int eBlocks = (E + TRE - 1) / TRE;
    hipLaunchKernelGGL(edge_mlp_kernel, dim3(eBlocks), dim3(256),
                       SM_DW * sizeof(float), stream,
                       node, efeat, snd, rcv, ew1, eb1, ew2, eb2, ew3, eb3,
                       eg, ebeta, out_e, agg, E);

    const int nBlocks = (N + TR - 1) / TR;
    hipLaunchKernelGGL(node_mlp_kernel, dim3(nBlocks), dim3(256), 0, stream,
                       node, agg, nw1, nb1, nw2, nb2, nw3, nb3,
                       ng, nbeta, out_n, N);
}